// Round 13
// baseline (1058.104 us; speedup 1.0000x reference)
//
#include <hip/hip_runtime.h>
#include <hip/hip_fp16.h>
#include <math.h>

// Problem constants
#define ROWS   8192        // B*L = 2*4096
#define DIMK   2048
#define HIDN   4096
#define QCH    128
#define NCHUNK 32          // L/Q per batch
#define CST    136         // chunk-kernel LDS row stride (shorts)
#define RST    68          // raw-tile LDS row stride (shorts)

typedef __attribute__((ext_vector_type(8))) short short8;
typedef __attribute__((ext_vector_type(8))) _Float16 half8;
typedef __attribute__((ext_vector_type(4))) float floatx4;

static __device__ inline unsigned short f2h(float f){
  union { _Float16 h; unsigned short u; } v; v.h = (_Float16)f; return v.u;
}
static __device__ inline float h2f(unsigned short u){
  union { unsigned short u; _Float16 h; } v; v.u = u; return (float)v.h;
}
static __device__ inline void async_cp16(const void* g, void* l){
  __builtin_amdgcn_global_load_lds((const __attribute__((address_space(1))) void*)g,
                                   (__attribute__((address_space(3))) void*)l, 16, 0, 0);
}

// ---------------- merged fp32 -> fp16 cast for x, W_in[0:8448], W_out ----------
__global__ void k_prep(const float* __restrict__ x, const float* __restrict__ Win,
                       const float* __restrict__ Wout, unsigned short* __restrict__ xw,
                       unsigned short* __restrict__ winb, unsigned short* __restrict__ woutb){
  int blk = blockIdx.x, t = threadIdx.x;
  const float* src; unsigned short* dst; int i;
  if (blk < 16384){ src = x;    dst = xw;    i = blk * 256 + t; }
  else if (blk < 33280){ src = Win;  dst = winb;  i = (blk - 16384) * 256 + t; }
  else { src = Wout; dst = woutb; i = (blk - 33280) * 256 + t; }
  float4 v = ((const float4*)src)[i];
  unsigned long long p = (unsigned long long)f2h(v.x)
                       | ((unsigned long long)f2h(v.y) << 16)
                       | ((unsigned long long)f2h(v.z) << 32)
                       | ((unsigned long long)f2h(v.w) << 48);
  ((unsigned long long*)dst)[i] = p;
}

// ---------------- exact fp32 dt_raw = x @ W_in[8448:8512].T ----------------
#define DT_KT 128
__global__ __launch_bounds__(256)
void k_dtraw(const float* __restrict__ x, const float* __restrict__ Win,
             float* __restrict__ dtraw){
  __shared__ float ws[64 * (DT_KT + 4)];          // stride 132 floats
  const int t = threadIdx.x;
  const int lane = t & 63, w = t >> 6;
  const int r0 = blockIdx.x * 8;
  const int rw = __builtin_amdgcn_readfirstlane(r0 + w * 2);
  float acc0 = 0.f, acc1 = 0.f;
  for (int k0 = 0; k0 < DIMK; k0 += DT_KT){
    __syncthreads();                              // previous tile's reads done
#pragma unroll
    for (int l = 0; l < 8; l++){
      int fidx = (l * 256 + t) * 4;               // 0..8191 floats
      int row = fidx >> 7, col = fidx & 127;
      *(float4*)&ws[row * 132 + col] =
          *(const float4*)&Win[(size_t)(8448 + row) * DIMK + k0 + col];
    }
    __syncthreads();
    const float* xa = x + (size_t)rw * DIMK + k0;
    const float* xb = xa + DIMK;
#pragma unroll 8
    for (int kk = 0; kk < DT_KT; kk += 4){
      float4 wv = *(const float4*)&ws[lane * 132 + kk];
      float4 va = *(const float4*)&xa[kk];
      float4 vb = *(const float4*)&xb[kk];
      acc0 += wv.x*va.x + wv.y*va.y + wv.z*va.z + wv.w*va.w;
      acc1 += wv.x*vb.x + wv.y*vb.y + wv.z*vb.z + wv.w*vb.w;
    }
  }
  dtraw[(size_t)rw * 64 + lane]       = acc0;
  dtraw[(size_t)(rw + 1) * 64 + lane] = acc1;
}

// ---------------- asm LDS read helpers (opaque to alias analysis) ----------------
static __device__ inline unsigned ldsaddr(const void* p){
  return (unsigned)(size_t)(const __attribute__((address_space(3))) void*)p;
}
static __device__ inline floatx4 dsr128(unsigned a){
  floatx4 d;
  asm volatile("ds_read_b128 %0, %1" : "=v"(d) : "v"(a));
  return d;
}
static __device__ inline half8 as_h8(floatx4 f){
  union { floatx4 f; half8 h; } u; u.f = f; return u.h;
}

// ---------------- 256x256 MFMA GEMM core, 4-phase/K-tile (R7 local optimum) ----
template<int KD>
__device__ inline void gemm256_core(const unsigned short* __restrict__ A,
                                    const unsigned short* __restrict__ B,
                                    int row0, int col0,
                                    unsigned short* sA, unsigned short* sB,
                                    floatx4 (&acc)[8][4], int t){
  const int lane = t & 63, wid = t >> 6;
  const int wm = wid >> 2, wn = wid & 3;
  const int quad = lane >> 4, l16 = lane & 15;
  const int srow  = t >> 3;                    // 0..63: row within 64-row stage block
  const int sslot = (t & 7) ^ (srow & 7);      // pre-swizzled global 16B slot
  constexpr int NT = KD / 64;

  auto stageA = [&](int d, int half, int kt){
    unsigned short* dst = sA + d*256*64 + half*128*64;
    const unsigned short* src = A + (size_t)(row0 + half*128) * KD + kt*64;
#pragma unroll
    for (int i = 0; i < 2; i++)
      async_cp16(src + (size_t)(i*64 + srow) * KD + sslot*8,
                 dst + ((size_t)i*512 + t)*8);
  };
  auto stageB = [&](int d, int half, int kt){
    unsigned short* dst = sB + d*256*64 + half*128*64;
    const unsigned short* src = B + (size_t)(col0 + half*128) * KD + kt*64;
#pragma unroll
    for (int i = 0; i < 2; i++)
      async_cp16(src + (size_t)(i*64 + srow) * KD + sslot*8,
                 dst + ((size_t)i*512 + t)*8);
  };

  const unsigned sAbase = ldsaddr(sA), sBbase = ldsaddr(sB);
  floatx4 af[8][2], bf[4][2];
  auto rdA = [&](unsigned base, int fr, int ks) -> floatx4 {
    return dsr128(base + 2u*(unsigned)((fr*16 + l16)*64 + (((ks*4+quad)^(l16&7))*8)));
  };
  auto rdB = [&](unsigned base, int fc, int ks) -> floatx4 {
    return dsr128(base + 2u*(unsigned)((fc*16 + l16)*64 + (((ks*4+quad)^(l16&7))*8)));
  };
  auto mmac = [&](int mh, int nh){
    __builtin_amdgcn_s_setprio(1);
#pragma unroll
    for (int mm = 0; mm < 4; mm++)
#pragma unroll
      for (int nn = 0; nn < 2; nn++)
#pragma unroll
        for (int ks = 0; ks < 2; ks++)
          acc[mh*4+mm][nh*2+nn] = __builtin_amdgcn_mfma_f32_16x16x32_f16(
              as_h8(af[mh*4+mm][ks]), as_h8(bf[nh*2+nn][ks]), acc[mh*4+mm][nh*2+nn], 0, 0, 0);
    __builtin_amdgcn_s_setprio(0);
  };

  // prologue: tile0 full -> buf0 (8 loads), tile1 A -> buf1 (4 loads)
  stageA(0,0,0); stageA(0,1,0); stageB(0,0,0); stageB(0,1,0);
  stageA(1,0,1); stageA(1,1,1);
  asm volatile("s_waitcnt vmcnt(4)" ::: "memory");   // tile0's 8 loads landed
  __builtin_amdgcn_s_barrier();

  for (int T = 0; T < NT; T++){
    const int cur = T & 1;
    const unsigned aAd = sAbase + 2u*(unsigned)(cur*256*64 + wm*128*64);
    const unsigned bAd = sBbase + 2u*(unsigned)(cur*256*64 + wn*64*64);
    // ---------------- phase 0: read A0-3,B0-1 | stage B-top(T+1) ----------------
#pragma unroll
    for (int fr = 0; fr < 4; fr++)
#pragma unroll
      for (int ks = 0; ks < 2; ks++)
        af[fr][ks] = rdA(aAd, fr, ks);
#pragma unroll
    for (int fc = 0; fc < 2; fc++)
#pragma unroll
      for (int ks = 0; ks < 2; ks++)
        bf[fc][ks] = rdB(bAd, fc, ks);
    if (T + 1 < NT) stageB(cur^1, 0, T+1);
    __builtin_amdgcn_s_barrier();
    asm volatile("s_waitcnt lgkmcnt(0)" ::: "memory");
    __builtin_amdgcn_sched_barrier(0);
    mmac(0, 0);
    __builtin_amdgcn_s_barrier();
    // ---------------- phase 1: read A4-7 | stage B-bot(T+1) ----------------
#pragma unroll
    for (int fr = 4; fr < 8; fr++)
#pragma unroll
      for (int ks = 0; ks < 2; ks++)
        af[fr][ks] = rdA(aAd, fr, ks);
    if (T + 1 < NT) stageB(cur^1, 1, T+1);
    __builtin_amdgcn_s_barrier();
    asm volatile("s_waitcnt lgkmcnt(0)" ::: "memory");
    __builtin_amdgcn_sched_barrier(0);
    mmac(1, 0);
    __builtin_amdgcn_s_barrier();
    // ---------------- phase 2: read B2-3 ----------------
#pragma unroll
    for (int fc = 2; fc < 4; fc++)
#pragma unroll
      for (int ks = 0; ks < 2; ks++)
        bf[fc][ks] = rdB(bAd, fc, ks);
    __builtin_amdgcn_s_barrier();
    asm volatile("s_waitcnt lgkmcnt(0)" ::: "memory");
    __builtin_amdgcn_sched_barrier(0);
    mmac(0, 1);
    __builtin_amdgcn_s_barrier();
    // ---------------- phase 3: stage A(T+2), counted vmcnt ----------------
    if (T + 2 < NT){
      stageA(cur, 0, T+2); stageA(cur, 1, T+2);
      asm volatile("s_waitcnt vmcnt(4)" ::: "memory");
    } else if (T + 1 < NT){
      asm volatile("s_waitcnt vmcnt(0)" ::: "memory");
    }
    __builtin_amdgcn_s_barrier();
    mmac(1, 1);
    __builtin_amdgcn_s_barrier();
  }
}

// ---------------- 128x128 MFMA GEMM core (R0-R2, harness-verified) ------------
__device__ inline void gemm128_core(const unsigned short* __restrict__ A,
                                    const unsigned short* __restrict__ B,
                                    int Kd, int row0, int col0,
                                    unsigned short* lA, unsigned short* lB,
                                    floatx4 (&acc)[4][4], int t){
  const int w = t >> 6, lane = t & 63;
  const int quad = lane >> 4, l16 = lane & 15;
  const int wr = (w >> 1) * 64, wc = (w & 1) * 64;
  for (int k0 = 0; k0 < Kd; k0 += 64){
#pragma unroll
    for (int i = 0; i < 4; i++){
      int cb = i * 256 + w * 64, c = cb + lane;
      async_cp16(A + (size_t)(row0 + (c >> 3)) * Kd + k0 + (c & 7) * 8, lA + (size_t)cb * 8);
    }
#pragma unroll
    for (int i = 0; i < 4; i++){
      int cb = i * 256 + w * 64, c = cb + lane;
      async_cp16(B + (size_t)(col0 + (c >> 3)) * Kd + k0 + (c & 7) * 8, lB + (size_t)cb * 8);
    }
    __syncthreads();
#pragma unroll
    for (int ks = 0; ks < 2; ks++){
      half8 af[4], bfr[4];
#pragma unroll
      for (int i = 0; i < 4; i++){
        af[i]  = *(const half8*)&lA[(wr + i*16 + l16)*64 + ks*32 + quad*8];
        bfr[i] = *(const half8*)&lB[(wc + i*16 + l16)*64 + ks*32 + quad*8];
      }
#pragma unroll
      for (int i = 0; i < 4; i++)
#pragma unroll
        for (int j = 0; j < 4; j++)
          acc[i][j] = __builtin_amdgcn_mfma_f32_16x16x32_f16(af[i], bfr[j], acc[i][j], 0, 0, 0);
    }
    __syncthreads();
  }
}

// ---------------- GEMM1 main: cols 0..8192 (z | xs), 1024 blocks = 4.0 rounds --
__global__ __launch_bounds__(512, 2)
void k_gemm1(const unsigned short* __restrict__ A, const unsigned short* __restrict__ B,
             unsigned short* __restrict__ zbuf, unsigned short* __restrict__ xsraw){
  __shared__ __align__(16) unsigned short sA[2*256*64];
  __shared__ __align__(16) unsigned short sB[2*256*64];
  const int t = threadIdx.x;
  // bijective XCD swizzle: 1024 = 8 * 128
  int swz = (blockIdx.x % 8) * 128 + blockIdx.x / 8;
  const int row0 = (swz & 31) * 256, col0 = (swz >> 5) * 256;
  floatx4 acc[8][4] = {};
  gemm256_core<DIMK>(A, B, row0, col0, sA, sB, acc, t);
  const int lane = t & 63, wid = t >> 6;
  const int wm = wid >> 2, wn = wid & 3;
  const int quad = lane >> 4, l16 = lane & 15;
  unsigned short* dst; int cbase;
  if (col0 < 4096){ dst = zbuf; cbase = 0; }
  else { dst = xsraw; cbase = 4096; }
#pragma unroll
  for (int m = 0; m < 8; m++)
#pragma unroll
    for (int n = 0; n < 4; n++){
      int rb = row0 + wm*128 + m*16 + quad*4;
      int cc = col0 + wn*64 + n*16 + l16 - cbase;
#pragma unroll
      for (int r = 0; r < 4; r++)
        dst[(size_t)(rb + r) * 4096 + cc] = f2h(acc[m][n][r]);
    }
}

// ---------------- GEMM1 bc panel: cols 8192..8448 -> bcraw, 128 quarter blocks --
__global__ __launch_bounds__(256, 2)
void k_gemm1bc(const unsigned short* __restrict__ A, const unsigned short* __restrict__ B,
               unsigned short* __restrict__ bcraw){
  __shared__ __align__(16) unsigned short lA[128*64];
  __shared__ __align__(16) unsigned short lB[128*64];
  const int t = threadIdx.x;
  const int row0 = blockIdx.y * 128, col0 = 8192 + blockIdx.x * 128;
  floatx4 acc[4][4] = {};
  gemm128_core(A, B, DIMK, row0, col0, lA, lB, acc, t);
  const int w = t >> 6, lane = t & 63, quad = lane >> 4, l16 = lane & 15;
  const int wr = (w >> 1) * 64, wc = (w & 1) * 64;
#pragma unroll
  for (int i = 0; i < 4; i++)
#pragma unroll
    for (int j = 0; j < 4; j++){
      int rb = row0 + wr + i*16 + quad*4;
      int cc = col0 + wc + j*16 + l16 - 8192;
#pragma unroll
      for (int r = 0; r < 4; r++)
        bcraw[(size_t)(rb + r) * 256 + cc] = f2h(acc[i][j][r]);
    }
}

// ---------------- GEMM2: fp32 epilogue to d_out ----------------
__global__ __launch_bounds__(512, 2)
void k_gemm2(const unsigned short* __restrict__ A, const unsigned short* __restrict__ B,
             float* __restrict__ C){
  __shared__ __align__(16) unsigned short sA[2*256*64];
  __shared__ __align__(16) unsigned short sB[2*256*64];
  const int t = threadIdx.x;
  // bijective XCD swizzle: 256 = 8 * 32
  int swz = (blockIdx.x % 8) * 32 + blockIdx.x / 8;
  const int row0 = (swz & 31) * 256, col0 = (swz >> 5) * 256;
  floatx4 acc[8][4] = {};
  gemm256_core<HIDN>(A, B, row0, col0, sA, sB, acc, t);
  const int lane = t & 63, wid = t >> 6;
  const int wm = wid >> 2, wn = wid & 3;
  const int quad = lane >> 4, l16 = lane & 15;
#pragma unroll
  for (int m = 0; m < 8; m++)
#pragma unroll
    for (int n = 0; n < 4; n++){
      int rb = row0 + wm*128 + m*16 + quad*4;
      int cc = col0 + wn*64 + n*16 + l16;
#pragma unroll
      for (int r = 0; r < 4; r++)
        C[(size_t)(rb + r) * DIMK + cc] = acc[m][n][r];
    }
}

// ---------------- merged post-gemm1 small kernels ----------------
__global__ void k_mid(const unsigned short* __restrict__ bcraw, const float* __restrict__ cw,
                      unsigned short* __restrict__ bcc,
                      const unsigned short* __restrict__ xsraw, unsigned short* __restrict__ halo,
                      const float* __restrict__ dtraw, const float* __restrict__ dtbias,
                      const float* __restrict__ Alog, float* __restrict__ dtb,
                      float* __restrict__ cumb){
  int blk = blockIdx.x, t = threadIdx.x;
  if (blk < 8192){
    int row = blk, c = t;
    int tl = row & 4095;
    const float4 wv = *(const float4*)&cw[(size_t)(4096 + c) * 4];
    const unsigned short* col = bcraw + c;
    size_t rb = (size_t)row * 256;
    float a = h2f(col[rb]) * wv.w;
    if (tl >= 1) a += h2f(col[rb - 256]) * wv.z;
    if (tl >= 2) a += h2f(col[rb - 512]) * wv.y;
    if (tl >= 3) a += h2f(col[rb - 768]) * wv.x;
    bcc[rb + c] = f2h(a / (1.f + __expf(-a)));
  } else if (blk < 11264){
    int idx = blk - 8192;                       // [0,3072) = 16 x 3 x 64
    int col = (idx & 15) * 256 + t;
    int slot = (idx >> 4) % 3;
    int bc = idx / 48;
    long r = (long)bc * QCH - 3 + slot;
    if (r >= 0)
      halo[((size_t)bc * 3 + slot) * 4096 + col] = xsraw[(size_t)r * 4096 + col];
  } else {
    int lb = blk - 11264;                       // [0,16): 4 chunks x 64 heads per block
    int bc = lb * 4 + (t >> 6);
    int h = t & 63;
    float bias = dtbias[h];
    float A = -__expf(Alog[h]);
    float run = 0.f;
    size_t rowb = (size_t)bc * QCH;
    for (int q = 0; q < QCH; q++){
      float dr = dtraw[(rowb + q) * 64 + h] + bias;
      float dt = dr > 20.f ? dr : log1pf(__expf(dr));
      dtb[(rowb + q) * 64 + h] = dt;
      run += dt * A;
      cumb[(rowb + q) * 64 + h] = run;
    }
  }
}

// ---------------- per-(chunk,head): CB -> M -> Yd; + Yoff from Sprev; y = Yd+Yoff+D*xs ----------------
// xsc = POST-conv xs (chunk2 wrote it back in place over xsraw) in [row][col] layout.
__global__ __launch_bounds__(256, 2)
void k_chunk1(const unsigned short* __restrict__ xsc, const unsigned short* __restrict__ bcc,
              const float* __restrict__ dtb, const float* __restrict__ cumb,
              const float* __restrict__ Dp, const unsigned short* __restrict__ st,
              unsigned short* __restrict__ ybuf){
  __shared__ __align__(16) unsigned short Ml[128*CST];
  __shared__ __align__(16) unsigned short xsT[64*CST];
  __shared__ float cum_s[128], dt_s[128];
  const int blk = blockIdx.x, h = blk & 63, bc = blk >> 6;
  const size_t rowb = (size_t)bc * QCH;
  const int t = threadIdx.x, w = t >> 6, lane = t & 63, quad = lane >> 4, l16 = lane & 15;
  const int wrow = w * 32;
  if (t < 128){ cum_s[t] = cumb[(rowb + t)*64 + h]; dt_s[t] = dtb[(rowb + t)*64 + h]; }
  __syncthreads();
  // copy-transpose post-conv xs tile into xsT (no conv recompute)
#pragma unroll
  for (int it = 0; it < 2; it++){
    int idx = it * 256 + t;
    int q = idx & 127, p0 = (idx >> 7) * 16;
    const unsigned short* cur = xsc + (rowb + q) * 4096 + h * 64 + p0;
    short8 c0 = *(const short8*)cur, c1 = *(const short8*)(cur + 8);
#pragma unroll
    for (int j = 0; j < 16; j++)
      xsT[(p0 + j) * CST + q] = (unsigned short)(j < 8 ? c0[j] : c1[j-8]);
  }
  // CB = C @ B^T from post-conv bcc
  floatx4 acc[2][8] = {};
  const unsigned short* Cb = bcc + rowb * 256 + 128;
  const unsigned short* Bb = bcc + rowb * 256;
#pragma unroll
  for (int ks = 0; ks < 4; ks++){
    half8 af[2];
#pragma unroll
    for (int i = 0; i < 2; i++)
      af[i] = *(const half8*)(Cb + (size_t)(wrow + i*16 + l16) * 256 + ks*32 + quad*8);
#pragma unroll
    for (int j = 0; j < 8; j++){
      half8 bfr = *(const half8*)(Bb + (size_t)(j*16 + l16) * 256 + ks*32 + quad*8);
#pragma unroll
      for (int i = 0; i < 2; i++)
        acc[i][j] = __builtin_amdgcn_mfma_f32_16x16x32_f16(af[i], bfr, acc[i][j], 0, 0, 0);
    }
  }
  // M = CB * exp(cum_i - cum_j) * dt_j, causal, -> LDS fp16
#pragma unroll
  for (int i = 0; i < 2; i++)
#pragma unroll
    for (int j = 0; j < 8; j++){
      int jc = j*16 + l16;
      float dtj = dt_s[jc], cj = cum_s[jc];
#pragma unroll
      for (int r = 0; r < 4; r++){
        int ir = wrow + i*16 + quad*4 + r;
        float m = (ir >= jc) ? acc[i][j][r] * __expf(cum_s[ir] - cj) * dtj : 0.f;
        Ml[ir * CST + jc] = f2h(m);
      }
    }
  __syncthreads();
  // Yd = M @ xs
  floatx4 accY[2][4] = {};
#pragma unroll
  for (int ks = 0; ks < 4; ks++){
    half8 af[2], bfr[4];
#pragma unroll
    for (int i = 0; i < 2; i++)
      af[i] = *(const half8*)&Ml[(wrow + i*16 + l16)*CST + ks*32 + quad*8];
#pragma unroll
    for (int p = 0; p < 4; p++)
      bfr[p] = *(const half8*)&xsT[(p*16 + l16)*CST + ks*32 + quad*8];
#pragma unroll
    for (int i = 0; i < 2; i++)
#pragma unroll
      for (int p = 0; p < 4; p++)
        accY[i][p] = __builtin_amdgcn_mfma_f32_16x16x32_f16(af[i], bfr[p], accY[i][p], 0, 0, 0);
  }
  // ---- Yoff: stage Sprev (fp16) into Ml's LDS (stride CST), then C @ Sprev^T ----
  __syncthreads();                       // all Yd reads of Ml done
  unsigned short* Sp = Ml;               // reuse (64*CST <= 128*CST)
  {
    size_t base = ((size_t)bc * 64 + h) * 8192;
#pragma unroll
    for (int it = 0; it < 4; it++){
      int flat = it * 256 + t;           // [0,1024): 64 rows x 16 copies of 8
      int row = flat >> 4, col = (flat & 15) * 8;
      *(short8*)&Sp[row * CST + col] = *(const short8*)&st[base + (size_t)row * 128 + col];
    }
  }
  __syncthreads();
  floatx4 accO[2][4] = {};
#pragma unroll
  for (int ks = 0; ks < 4; ks++){
    half8 af[2], bfr[4];
#pragma unroll
    for (int i = 0; i < 2; i++)
      af[i] = *(const half8*)(Cb + (size_t)(wrow + i*16 + l16) * 256 + ks*32 + quad*8);
#pragma unroll
    for (int p = 0; p < 4; p++)
      bfr[p] = *(const half8*)&Sp[(p*16 + l16)*CST + ks*32 + quad*8];
#pragma unroll
    for (int i = 0; i < 2; i++)
#pragma unroll
      for (int p = 0; p < 4; p++)
        accO[i][p] = __builtin_amdgcn_mfma_f32_16x16x32_f16(af[i], bfr[p], accO[i][p], 0, 0, 0);
  }
  // ---- epilogue: y -> LDS (reuse Ml after all Sp reads), then coalesced store ----
  __syncthreads();                       // all accO reads of Sp(=Ml) done
  unsigned short* yl = Ml;               // [128 rows][stride 68]
  float Dh = Dp[h];
#pragma unroll
  for (int i = 0; i < 2; i++)
#pragma unroll
    for (int p = 0; p < 4; p++){
      int pc = p*16 + l16;
#pragma unroll
      for (int r = 0; r < 4; r++){
        int ir = wrow + i*16 + quad*4 + r;
        float y = accY[i][p][r] + __expf(cum_s[ir]) * accO[i][p][r] + Dh * h2f(xsT[pc*CST + ir]);
        yl[ir * 68 + pc] = f2h(y);
      }
    }
  __syncthreads();
#pragma unroll
  for (int it = 0; it < 4; it++){
    int flat = it * 256 + t;             // [0,1024): 128 rows x 8 slots of 8
    int row = flat >> 3, slot = (flat & 7) * 8;
    short8 v = *(const short8*)&yl[row * 68 + slot];
    *(short8*)&ybuf[(rowb + row) * (size_t)HIDN + h*64 + slot] = v;
  }
}

// ---------------- per-(chunk,head): states[p][n] = sum_q xs[q][p]*wdec_q*B[q][n] ----------------
// Raw-tile staging; post-conv written back to global from registers.
__global__ __launch_bounds__(256, 2)
void k_chunk2(unsigned short* __restrict__ xsraw, const unsigned short* __restrict__ bcc,
              const unsigned short* __restrict__ halo, const float* __restrict__ cw,
              const float* __restrict__ dtb, const float* __restrict__ cumb,
              unsigned short* __restrict__ st){
  __shared__ __align__(16) unsigned short wBT[128*CST];
  __shared__ __align__(16) unsigned short xsT[64*CST];
  __shared__ __align__(16) unsigned short xsRaw[131*RST];
  __shared__ float cum_s[128], dt_s[128];
  __shared__ float cws[64*4];
  const int blk = blockIdx.x, h = blk & 63, bc = blk >> 6;
  const size_t rowb = (size_t)bc * QCH;
  const int t = threadIdx.x, w = t >> 6, lane = t & 63, quad = lane >> 4, l16 = lane & 15;
  if (t < 128){ cum_s[t] = cumb[(rowb + t)*64 + h]; dt_s[t] = dtb[(rowb + t)*64 + h]; }
  if (t < 64) *(float4*)&cws[t*4] = *(const float4*)&cw[((size_t)h*64 + t)*4];
  // stage raw slice: 131 rows x 8 chunks of 16B = 1048 chunks
#pragma unroll
  for (int it = 0; it < 5; it++){
    int flat = it * 256 + t;
    if (flat < 1048){
      int row = flat >> 3, c8 = (flat & 7) * 8;
      const unsigned short* src = (row < 3)
        ? halo + ((size_t)bc * 3 + row) * 4096 + h * 64 + c8
        : xsraw + (rowb + row - 3) * 4096 + h * 64 + c8;
      *(short8*)&xsRaw[row * RST + c8] = *(const short8*)src;
    }
  }
  __syncthreads();
  // conv + SiLU from LDS; write xsT (transposed) + post-conv back to global
  const int tl0 = (bc & 31) * QCH;
#pragma unroll
  for (int it = 0; it < 2; it++){
    int idx = it * 256 + t;
    int q = idx & 127, p0 = (idx >> 7) * 16;
    int tl = tl0 + q;
    int lr = q + 3;
    float f1 = (tl >= 1) ? 1.f : 0.f;
    float f2 = (tl >= 2) ? 1.f : 0.f;
    float f3 = (tl >= 3) ? 1.f : 0.f;
    short8 c0 = *(const short8*)&xsRaw[lr*RST + p0],     c1 = *(const short8*)&xsRaw[lr*RST + p0 + 8];
    short8 a0 = *(const short8*)&xsRaw[(lr-1)*RST + p0], a1 = *(const short8*)&xsRaw[(lr-1)*RST + p0 + 8];
    short8 b0 = *(const short8*)&xsRaw[(lr-2)*RST + p0], b1 = *(const short8*)&xsRaw[(lr-2)*RST + p0 + 8];
    short8 d0 = *(const short8*)&xsRaw[(lr-3)*RST + p0], d1 = *(const short8*)&xsRaw[(lr-3)*RST + p0 + 8];
    short8 w0, w1;
#pragma unroll
    for (int j = 0; j < 16; j++){
      int col = p0 + j;
      const float* wp = cws + col * 4;
      float vc = h2f((unsigned short)(j < 8 ? c0[j] : c1[j-8]));
      float v1 = h2f((unsigned short)(j < 8 ? a0[j] : a1[j-8]));
      float v2 = h2f((unsigned short)(j < 8 ? b0[j] : b1[j-8]));
      float v3 = h2f((unsigned short)(j < 8 ? d0[j] : d1[j-8]));
      float a = vc * wp[3] + f1 * v1 * wp[2] + f2 * v2 * wp[1] + f3 * v3 * wp[0];
      float s = a / (1.f + __expf(-a));
      unsigned short hv = f2h(s);
      xsT[col * CST + q] = hv;
      if (j < 8) w0[j] = (short)hv; else w1[j-8] = (short)hv;
    }
    unsigned short* g = xsraw + (rowb + q) * 4096 + h * 64 + p0;
    *(short8*)g = w0;
    *(short8*)(g + 8) = w1;
  }
  float clast = cum_s[127];
#pragma unroll
  for (int it = 0; it < 2; it++){                 // wBT[n][q] = B[q][n]*wdec_q
    int idx = it * 256 + t;
    int q = idx & 127, n0 = (idx >> 7) * 32;
    float wd = __expf(clast - cum_s[q]) * dt_s[q];
    const unsigned short* gp = bcc + (rowb + q) * 256 + n0;
#pragma unroll
    for (int c4 = 0; c4 < 4; c4++){
      short8 v = *(const short8*)(gp + c4*8);
#pragma unroll
      for (int jj = 0; jj < 8; jj++)
        wBT[(n0 + c4*8 + jj)*CST + q] = f2h(h2f((unsigned short)v[jj]) * wd);
    }
  }
  __syncthreads();
  floatx4 acc[8] = {};
#pragma unroll
  for (int ks = 0; ks < 4; ks++){
    half8 af = *(const half8*)&xsT[(w*16 + l16)*CST + ks*32 + quad*8];
#pragma unroll
    for (int j = 0; j < 8; j++){
      half8 bfr = *(const half8*)&wBT[(j*16 + l16)*CST + ks*32 + quad*8];
      acc[j] = __builtin_amdgcn_mfma_f32_16x16x32_f16(af, bfr, acc[j], 0, 0, 0);
    }
  }
  size_t base = ((size_t)bc * 64 + h) * 8192;
#pragma unroll
  for (int j = 0; j < 8; j++){
    int n = j*16 + l16;
#pragma unroll
    for (int r = 0; r < 4; r++){
      int p = w*16 + quad*4 + r;
      st[base + p*128 + n] = f2h(acc[j][r]);
    }
  }
}

// ---------------- sequential inter-chunk scan (fp16 states -> Sprev, in place) ----------------
__global__ void k_scan(unsigned short* __restrict__ st, const float* __restrict__ cumb){
  int id = blockIdx.x * 256 + threadIdx.x;  // [0, 2*64*64*64)
  int n2 = id & 63, p = (id >> 6) & 63, h = (id >> 12) & 63, b = id >> 18;
  float S0 = 0.f, S1 = 0.f;
  for (int c = 0; c < NCHUNK; c++){
    int bc = b * NCHUNK + c;
    size_t idx = ((size_t)bc * 64 + h) * 8192 + (size_t)p * 128 + n2 * 2;
    float dec = __expf(cumb[((size_t)bc * QCH + 127) * 64 + h]);
    unsigned v = *(const unsigned*)&st[idx];
    float v0 = h2f((unsigned short)(v & 0xffff));
    float v1 = h2f((unsigned short)(v >> 16));
    unsigned o = (unsigned)f2h(S0) | ((unsigned)f2h(S1) << 16);
    *(unsigned*)&st[idx] = o;
    S0 = S0 * dec + v0;
    S1 = S1 * dec + v1;
  }
}

// ---------------- gate y*silu(z) + RMSNorm, in-place fp16 (vectorized) ----------
__global__ __launch_bounds__(256)
void k_gate(unsigned short* __restrict__ yb, const unsigned short* __restrict__ zb,
            const float* __restrict__ nw){
  __shared__ float red[4];
  int row = blockIdx.x, t = threadIdx.x;
  size_t base = (size_t)row * HIDN + t * 16;
  short8 y0 = *(const short8*)&yb[base], y1 = *(const short8*)&yb[base + 8];
  short8 z0 = *(const short8*)&zb[base], z1 = *(const short8*)&zb[base + 8];
  float vals[16], ss = 0.f;
#pragma unroll
  for (int j = 0; j < 8; j++){
    float y = h2f((unsigned short)y0[j]);
    float z = h2f((unsigned short)z0[j]);
    float v = y * (z / (1.f + __expf(-z)));
    vals[j] = v; ss += v * v;
  }
#pragma unroll
  for (int j = 0; j < 8; j++){
    float y = h2f((unsigned short)y1[j]);
    float z = h2f((unsigned short)z1[j]);
    float v = y * (z / (1.f + __expf(-z)));
    vals[8 + j] = v; ss += v * v;
  }
  for (int o = 32; o > 0; o >>= 1) ss += __shfl_down(ss, o, 64);
  int w = t >> 6, lane = t & 63;
  if (lane == 0) red[w] = ss;
  __syncthreads();
  float scale = rsqrtf((red[0] + red[1] + red[2] + red[3]) / (float)HIDN + 1e-5f);
  const float4 nw0 = *(const float4*)&nw[t*16];
  const float4 nw1 = *(const float4*)&nw[t*16 + 4];
  const float4 nw2 = *(const float4*)&nw[t*16 + 8];
  const float4 nw3 = *(const float4*)&nw[t*16 + 12];
  float nwv[16] = { nw0.x, nw0.y, nw0.z, nw0.w, nw1.x, nw1.y, nw1.z, nw1.w,
                    nw2.x, nw2.y, nw2.z, nw2.w, nw3.x, nw3.y, nw3.z, nw3.w };
  short8 o0, o1;
#pragma unroll
  for (int j = 0; j < 8; j++){
    o0[j] = (short)f2h(vals[j] * scale * nwv[j]);
    o1[j] = (short)f2h(vals[8 + j] * scale * nwv[8 + j]);
  }
  *(short8*)&yb[base]     = o0;
  *(short8*)&yb[base + 8] = o1;
}

extern "C" void kernel_launch(void* const* d_in, const int* in_sizes, int n_in,
                              void* d_out, int out_size, void* d_ws, size_t ws_size,
                              hipStream_t stream){
  const float* x      = (const float*)d_in[0];
  const float* Win    = (const float*)d_in[1];
  const float* convw  = (const float*)d_in[2];
  const float* dtbias = (const float*)d_in[3];
  const float* Alog   = (const float*)d_in[4];
  const float* Dp     = (const float*)d_in[5];
  const float* nw     = (const float*)d_in[6];
  const float* Wout   = (const float*)d_in[7];
  float* out = (float*)d_out;

  char* ws = (char*)d_ws;
  size_t off = 0;
  auto alloc = [&](size_t bytes)->void*{ void* p = ws + off; off += (bytes + 255) & ~(size_t)255; return p; };
  unsigned short* xw    = (unsigned short*)alloc((size_t)ROWS * DIMK * 2);   // 33.5 MB (dead after gemm1)
  unsigned short* winb  = (unsigned short*)alloc((size_t)8448 * DIMK * 2);   // 34.6 MB (dead after gemm1)
  float*          dtraw = (float*)alloc((size_t)ROWS * 64 * 4);              // 2.1 MB
  unsigned short* woutb = (unsigned short*)alloc((size_t)DIMK * HIDN * 2);   // 16.8 MB
  unsigned short* zbuf  = (unsigned short*)alloc((size_t)ROWS * HIDN * 2);   // 67.1 MB
  unsigned short* xsraw = (unsigned short*)alloc((size_t)ROWS * HIDN * 2);   // 67.1 MB (pre-conv xs -> post-conv xs -> y)
  unsigned short* bcraw = (unsigned short*)alloc((size_t)ROWS * 256 * 2);    // 4.2 MB
  unsigned short* bcc   = (unsigned short*)alloc((size_t)ROWS * 256 * 2);    // 4.2 MB
  unsigned short* halo  = (unsigned short*)alloc((size_t)64 * 3 * 4096 * 2); // 1.5 MB
  float*          dtb   = (float*)alloc((size_t)ROWS * 64 * 4);              // 2.1 MB
  float*          cumb  = (float*)alloc((size_t)ROWS * 64 * 4);              // 2.1 MB
  // total ~224.5 MiB; states (fp16, 67.1 MB) overlays dead xw+winb region
  unsigned short* st    = xw;
  unsigned short* ybuf  = xsraw;   // chunk1 writes y in-place over post-conv xs

  k_prep<<<41472, 256, 0, stream>>>(x, Win, Wout, xw, winb, woutb);
  k_dtraw<<<ROWS/8, 256, 0, stream>>>(x, Win, dtraw);
  k_gemm1<<<dim3(1024), 512, 0, stream>>>(xw, winb, zbuf, xsraw);
  k_gemm1bc<<<dim3(2, 64), 256, 0, stream>>>(xw, winb, bcraw);
  k_mid<<<11280, 256, 0, stream>>>(bcraw, convw, bcc, xsraw, halo,
                                   dtraw, dtbias, Alog, dtb, cumb);
  k_chunk2<<<4096, 256, 0, stream>>>(xsraw, bcc, halo, convw, dtb, cumb, st);
  k_scan<<<2048, 256, 0, stream>>>(st, cumb);
  k_chunk1<<<4096, 256, 0, stream>>>(xsraw, bcc, dtb, cumb, Dp, st, ybuf);
  k_gate<<<ROWS, 256, 0, stream>>>(ybuf, zbuf, nw);
  k_gemm2<<<dim3(8*32), 512, 0, stream>>>(ybuf, woutb, out);
}

// Round 14
// 1042.745 us; speedup vs baseline: 1.0147x; 1.0147x over previous
//
#include <hip/hip_runtime.h>
#include <hip/hip_fp16.h>
#include <math.h>

// Problem constants
#define ROWS   8192        // B*L = 2*4096
#define DIMK   2048
#define HIDN   4096
#define QCH    128
#define NCHUNK 32          // L/Q per batch
#define CST    136         // chunk-kernel LDS row stride (shorts)
#define RST    68          // raw-tile LDS row stride (shorts)

typedef __attribute__((ext_vector_type(8))) short short8;
typedef __attribute__((ext_vector_type(8))) _Float16 half8;
typedef __attribute__((ext_vector_type(4))) float floatx4;

static __device__ inline unsigned short f2h(float f){
  union { _Float16 h; unsigned short u; } v; v.h = (_Float16)f; return v.u;
}
static __device__ inline float h2f(unsigned short u){
  union { unsigned short u; _Float16 h; } v; v.u = u; return (float)v.h;
}
static __device__ inline void async_cp16(const void* g, void* l){
  __builtin_amdgcn_global_load_lds((const __attribute__((address_space(1))) void*)g,
                                   (__attribute__((address_space(3))) void*)l, 16, 0, 0);
}

// ---------------- merged fp32 -> fp16 cast for x, W_in[0:8448], W_out ----------
__global__ void k_prep(const float* __restrict__ x, const float* __restrict__ Win,
                       const float* __restrict__ Wout, unsigned short* __restrict__ xw,
                       unsigned short* __restrict__ winb, unsigned short* __restrict__ woutb){
  int blk = blockIdx.x, t = threadIdx.x;
  const float* src; unsigned short* dst; int i;
  if (blk < 16384){ src = x;    dst = xw;    i = blk * 256 + t; }
  else if (blk < 33280){ src = Win;  dst = winb;  i = (blk - 16384) * 256 + t; }
  else { src = Wout; dst = woutb; i = (blk - 33280) * 256 + t; }
  float4 v = ((const float4*)src)[i];
  unsigned long long p = (unsigned long long)f2h(v.x)
                       | ((unsigned long long)f2h(v.y) << 16)
                       | ((unsigned long long)f2h(v.z) << 32)
                       | ((unsigned long long)f2h(v.w) << 48);
  ((unsigned long long*)dst)[i] = p;
}

// ---------------- exact fp32 dt_raw = x @ W_in[8448:8512].T ----------------
#define DT_KT 128
__global__ __launch_bounds__(256)
void k_dtraw(const float* __restrict__ x, const float* __restrict__ Win,
             float* __restrict__ dtraw){
  __shared__ float ws[64 * (DT_KT + 4)];          // stride 132 floats
  const int t = threadIdx.x;
  const int lane = t & 63, w = t >> 6;
  const int r0 = blockIdx.x * 8;
  const int rw = __builtin_amdgcn_readfirstlane(r0 + w * 2);
  float acc0 = 0.f, acc1 = 0.f;
  for (int k0 = 0; k0 < DIMK; k0 += DT_KT){
    __syncthreads();                              // previous tile's reads done
#pragma unroll
    for (int l = 0; l < 8; l++){
      int fidx = (l * 256 + t) * 4;               // 0..8191 floats
      int row = fidx >> 7, col = fidx & 127;
      *(float4*)&ws[row * 132 + col] =
          *(const float4*)&Win[(size_t)(8448 + row) * DIMK + k0 + col];
    }
    __syncthreads();
    const float* xa = x + (size_t)rw * DIMK + k0;
    const float* xb = xa + DIMK;
#pragma unroll 8
    for (int kk = 0; kk < DT_KT; kk += 4){
      float4 wv = *(const float4*)&ws[lane * 132 + kk];
      float4 va = *(const float4*)&xa[kk];
      float4 vb = *(const float4*)&xb[kk];
      acc0 += wv.x*va.x + wv.y*va.y + wv.z*va.z + wv.w*va.w;
      acc1 += wv.x*vb.x + wv.y*vb.y + wv.z*vb.z + wv.w*vb.w;
    }
  }
  dtraw[(size_t)rw * 64 + lane]       = acc0;
  dtraw[(size_t)(rw + 1) * 64 + lane] = acc1;
}

// ---------------- asm LDS read helpers (opaque to alias analysis) ----------------
static __device__ inline unsigned ldsaddr(const void* p){
  return (unsigned)(size_t)(const __attribute__((address_space(3))) void*)p;
}
static __device__ inline floatx4 dsr128(unsigned a){
  floatx4 d;
  asm volatile("ds_read_b128 %0, %1" : "=v"(d) : "v"(a));
  return d;
}
static __device__ inline half8 as_h8(floatx4 f){
  union { floatx4 f; half8 h; } u; u.f = f; return u.h;
}

// ---------------- 256x256 MFMA GEMM core, 4-phase/K-tile (R7 local optimum) ----
template<int KD>
__device__ inline void gemm256_core(const unsigned short* __restrict__ A,
                                    const unsigned short* __restrict__ B,
                                    int row0, int col0,
                                    unsigned short* sA, unsigned short* sB,
                                    floatx4 (&acc)[8][4], int t){
  const int lane = t & 63, wid = t >> 6;
  const int wm = wid >> 2, wn = wid & 3;
  const int quad = lane >> 4, l16 = lane & 15;
  const int srow  = t >> 3;                    // 0..63: row within 64-row stage block
  const int sslot = (t & 7) ^ (srow & 7);      // pre-swizzled global 16B slot
  constexpr int NT = KD / 64;

  auto stageA = [&](int d, int half, int kt){
    unsigned short* dst = sA + d*256*64 + half*128*64;
    const unsigned short* src = A + (size_t)(row0 + half*128) * KD + kt*64;
#pragma unroll
    for (int i = 0; i < 2; i++)
      async_cp16(src + (size_t)(i*64 + srow) * KD + sslot*8,
                 dst + ((size_t)i*512 + t)*8);
  };
  auto stageB = [&](int d, int half, int kt){
    unsigned short* dst = sB + d*256*64 + half*128*64;
    const unsigned short* src = B + (size_t)(col0 + half*128) * KD + kt*64;
#pragma unroll
    for (int i = 0; i < 2; i++)
      async_cp16(src + (size_t)(i*64 + srow) * KD + sslot*8,
                 dst + ((size_t)i*512 + t)*8);
  };

  const unsigned sAbase = ldsaddr(sA), sBbase = ldsaddr(sB);
  floatx4 af[8][2], bf[4][2];
  auto rdA = [&](unsigned base, int fr, int ks) -> floatx4 {
    return dsr128(base + 2u*(unsigned)((fr*16 + l16)*64 + (((ks*4+quad)^(l16&7))*8)));
  };
  auto rdB = [&](unsigned base, int fc, int ks) -> floatx4 {
    return dsr128(base + 2u*(unsigned)((fc*16 + l16)*64 + (((ks*4+quad)^(l16&7))*8)));
  };
  auto mmac = [&](int mh, int nh){
    __builtin_amdgcn_s_setprio(1);
#pragma unroll
    for (int mm = 0; mm < 4; mm++)
#pragma unroll
      for (int nn = 0; nn < 2; nn++)
#pragma unroll
        for (int ks = 0; ks < 2; ks++)
          acc[mh*4+mm][nh*2+nn] = __builtin_amdgcn_mfma_f32_16x16x32_f16(
              as_h8(af[mh*4+mm][ks]), as_h8(bf[nh*2+nn][ks]), acc[mh*4+mm][nh*2+nn], 0, 0, 0);
    __builtin_amdgcn_s_setprio(0);
  };

  // prologue: tile0 full -> buf0 (8 loads), tile1 A -> buf1 (4 loads)
  stageA(0,0,0); stageA(0,1,0); stageB(0,0,0); stageB(0,1,0);
  stageA(1,0,1); stageA(1,1,1);
  asm volatile("s_waitcnt vmcnt(4)" ::: "memory");   // tile0's 8 loads landed
  __builtin_amdgcn_s_barrier();

  for (int T = 0; T < NT; T++){
    const int cur = T & 1;
    const unsigned aAd = sAbase + 2u*(unsigned)(cur*256*64 + wm*128*64);
    const unsigned bAd = sBbase + 2u*(unsigned)(cur*256*64 + wn*64*64);
    // ---------------- phase 0: read A0-3,B0-1 | stage B-top(T+1) ----------------
#pragma unroll
    for (int fr = 0; fr < 4; fr++)
#pragma unroll
      for (int ks = 0; ks < 2; ks++)
        af[fr][ks] = rdA(aAd, fr, ks);
#pragma unroll
    for (int fc = 0; fc < 2; fc++)
#pragma unroll
      for (int ks = 0; ks < 2; ks++)
        bf[fc][ks] = rdB(bAd, fc, ks);
    if (T + 1 < NT) stageB(cur^1, 0, T+1);
    __builtin_amdgcn_s_barrier();
    asm volatile("s_waitcnt lgkmcnt(0)" ::: "memory");
    __builtin_amdgcn_sched_barrier(0);
    mmac(0, 0);
    __builtin_amdgcn_s_barrier();
    // ---------------- phase 1: read A4-7 | stage B-bot(T+1) ----------------
#pragma unroll
    for (int fr = 4; fr < 8; fr++)
#pragma unroll
      for (int ks = 0; ks < 2; ks++)
        af[fr][ks] = rdA(aAd, fr, ks);
    if (T + 1 < NT) stageB(cur^1, 1, T+1);
    __builtin_amdgcn_s_barrier();
    asm volatile("s_waitcnt lgkmcnt(0)" ::: "memory");
    __builtin_amdgcn_sched_barrier(0);
    mmac(1, 0);
    __builtin_amdgcn_s_barrier();
    // ---------------- phase 2: read B2-3 ----------------
#pragma unroll
    for (int fc = 2; fc < 4; fc++)
#pragma unroll
      for (int ks = 0; ks < 2; ks++)
        bf[fc][ks] = rdB(bAd, fc, ks);
    __builtin_amdgcn_s_barrier();
    asm volatile("s_waitcnt lgkmcnt(0)" ::: "memory");
    __builtin_amdgcn_sched_barrier(0);
    mmac(0, 1);
    __builtin_amdgcn_s_barrier();
    // ---------------- phase 3: stage A(T+2), counted vmcnt ----------------
    if (T + 2 < NT){
      stageA(cur, 0, T+2); stageA(cur, 1, T+2);
      asm volatile("s_waitcnt vmcnt(4)" ::: "memory");
    } else if (T + 1 < NT){
      asm volatile("s_waitcnt vmcnt(0)" ::: "memory");
    }
    __builtin_amdgcn_s_barrier();
    mmac(1, 1);
    __builtin_amdgcn_s_barrier();
  }
}

// ---------------- GEMM1 main: cols 0..8192 (z | xs), 1024 blocks = 4.0 rounds --
__global__ __launch_bounds__(512, 2)
void k_gemm1(const unsigned short* __restrict__ A, const unsigned short* __restrict__ B,
             unsigned short* __restrict__ zbuf, unsigned short* __restrict__ xsraw){
  __shared__ __align__(16) unsigned short sA[2*256*64];
  __shared__ __align__(16) unsigned short sB[2*256*64];
  const int t = threadIdx.x;
  // bijective XCD swizzle: 1024 = 8 * 128
  int swz = (blockIdx.x % 8) * 128 + blockIdx.x / 8;
  const int row0 = (swz & 31) * 256, col0 = (swz >> 5) * 256;
  floatx4 acc[8][4] = {};
  gemm256_core<DIMK>(A, B, row0, col0, sA, sB, acc, t);
  const int lane = t & 63, wid = t >> 6;
  const int wm = wid >> 2, wn = wid & 3;
  const int quad = lane >> 4, l16 = lane & 15;
  unsigned short* dst; int cbase;
  if (col0 < 4096){ dst = zbuf; cbase = 0; }
  else { dst = xsraw; cbase = 4096; }
#pragma unroll
  for (int m = 0; m < 8; m++)
#pragma unroll
    for (int n = 0; n < 4; n++){
      int rb = row0 + wm*128 + m*16 + quad*4;
      int cc = col0 + wn*64 + n*16 + l16 - cbase;
#pragma unroll
      for (int r = 0; r < 4; r++)
        dst[(size_t)(rb + r) * 4096 + cc] = f2h(acc[m][n][r]);
    }
}

// ---------------- GEMM1 bc panel: cols 8192..8448 -> bcraw ----------------
// 64x64 tiles, grid (4,128) = 512 blocks, 16KB LDS -> fully co-resident
// (R13's 128-block version was 0.5 blocks/CU, latency-bound, ~40 us).
// Same K order (k0 steps of 64, ks inner) -> bit-identical bc output.
__global__ __launch_bounds__(256)
void k_gemm1bc(const unsigned short* __restrict__ A, const unsigned short* __restrict__ B,
               unsigned short* __restrict__ bcraw){
  __shared__ __align__(16) unsigned short lA[64*64];
  __shared__ __align__(16) unsigned short lB[64*64];
  const int t = threadIdx.x;
  const int w = t >> 6, lane = t & 63;
  const int quad = lane >> 4, l16 = lane & 15;
  const int wr = (w >> 1) * 32, wc = (w & 1) * 32;
  const int row0 = blockIdx.y * 64, col0 = 8192 + blockIdx.x * 64;
  floatx4 acc[2][2] = {};
  for (int k0 = 0; k0 < DIMK; k0 += 64){
#pragma unroll
    for (int i = 0; i < 2; i++){
      int c = i * 256 + t;
      async_cp16(A + (size_t)(row0 + (c >> 3)) * DIMK + k0 + (c & 7) * 8, lA + (size_t)c * 8);
    }
#pragma unroll
    for (int i = 0; i < 2; i++){
      int c = i * 256 + t;
      async_cp16(B + (size_t)(col0 + (c >> 3)) * DIMK + k0 + (c & 7) * 8, lB + (size_t)c * 8);
    }
    __syncthreads();
#pragma unroll
    for (int ks = 0; ks < 2; ks++){
      half8 af[2], bfr[2];
#pragma unroll
      for (int i = 0; i < 2; i++){
        af[i]  = *(const half8*)&lA[(wr + i*16 + l16)*64 + ks*32 + quad*8];
        bfr[i] = *(const half8*)&lB[(wc + i*16 + l16)*64 + ks*32 + quad*8];
      }
#pragma unroll
      for (int i = 0; i < 2; i++)
#pragma unroll
        for (int j = 0; j < 2; j++)
          acc[i][j] = __builtin_amdgcn_mfma_f32_16x16x32_f16(af[i], bfr[j], acc[i][j], 0, 0, 0);
    }
    __syncthreads();
  }
#pragma unroll
  for (int i = 0; i < 2; i++)
#pragma unroll
    for (int j = 0; j < 2; j++){
      int rb = row0 + wr + i*16 + quad*4;
      int cc = col0 + wc + j*16 + l16 - 8192;
#pragma unroll
      for (int r = 0; r < 4; r++)
        bcraw[(size_t)(rb + r) * 256 + cc] = f2h(acc[i][j][r]);
    }
}

// ---------------- GEMM2: fp32 epilogue to d_out ----------------
__global__ __launch_bounds__(512, 2)
void k_gemm2(const unsigned short* __restrict__ A, const unsigned short* __restrict__ B,
             float* __restrict__ C){
  __shared__ __align__(16) unsigned short sA[2*256*64];
  __shared__ __align__(16) unsigned short sB[2*256*64];
  const int t = threadIdx.x;
  // bijective XCD swizzle: 256 = 8 * 32
  int swz = (blockIdx.x % 8) * 32 + blockIdx.x / 8;
  const int row0 = (swz & 31) * 256, col0 = (swz >> 5) * 256;
  floatx4 acc[8][4] = {};
  gemm256_core<HIDN>(A, B, row0, col0, sA, sB, acc, t);
  const int lane = t & 63, wid = t >> 6;
  const int wm = wid >> 2, wn = wid & 3;
  const int quad = lane >> 4, l16 = lane & 15;
#pragma unroll
  for (int m = 0; m < 8; m++)
#pragma unroll
    for (int n = 0; n < 4; n++){
      int rb = row0 + wm*128 + m*16 + quad*4;
      int cc = col0 + wn*64 + n*16 + l16;
#pragma unroll
      for (int r = 0; r < 4; r++)
        C[(size_t)(rb + r) * DIMK + cc] = acc[m][n][r];
    }
}

// ---------------- merged post-gemm1 small kernels ----------------
__global__ void k_mid(const unsigned short* __restrict__ bcraw, const float* __restrict__ cw,
                      unsigned short* __restrict__ bcc,
                      const unsigned short* __restrict__ xsraw, unsigned short* __restrict__ halo,
                      const float* __restrict__ dtraw, const float* __restrict__ dtbias,
                      const float* __restrict__ Alog, float* __restrict__ dtb,
                      float* __restrict__ cumb){
  int blk = blockIdx.x, t = threadIdx.x;
  if (blk < 8192){
    int row = blk, c = t;
    int tl = row & 4095;
    const float4 wv = *(const float4*)&cw[(size_t)(4096 + c) * 4];
    const unsigned short* col = bcraw + c;
    size_t rb = (size_t)row * 256;
    float a = h2f(col[rb]) * wv.w;
    if (tl >= 1) a += h2f(col[rb - 256]) * wv.z;
    if (tl >= 2) a += h2f(col[rb - 512]) * wv.y;
    if (tl >= 3) a += h2f(col[rb - 768]) * wv.x;
    bcc[rb + c] = f2h(a / (1.f + __expf(-a)));
  } else if (blk < 11264){
    int idx = blk - 8192;                       // [0,3072) = 16 x 3 x 64
    int col = (idx & 15) * 256 + t;
    int slot = (idx >> 4) % 3;
    int bc = idx / 48;
    long r = (long)bc * QCH - 3 + slot;
    if (r >= 0)
      halo[((size_t)bc * 3 + slot) * 4096 + col] = xsraw[(size_t)r * 4096 + col];
  } else {
    int lb = blk - 11264;                       // [0,16): 4 chunks x 64 heads per block
    int bc = lb * 4 + (t >> 6);
    int h = t & 63;
    float bias = dtbias[h];
    float A = -__expf(Alog[h]);
    float run = 0.f;
    size_t rowb = (size_t)bc * QCH;
    for (int q = 0; q < QCH; q++){
      float dr = dtraw[(rowb + q) * 64 + h] + bias;
      float dt = dr > 20.f ? dr : log1pf(__expf(dr));
      dtb[(rowb + q) * 64 + h] = dt;
      run += dt * A;
      cumb[(rowb + q) * 64 + h] = run;
    }
  }
}

// ---------------- per-(chunk,head): CB -> M -> Yd; + Yoff from Sprev; y = Yd+Yoff+D*xs ----------------
// xsc = POST-conv xs (chunk2 wrote it back in place over xsraw) in [row][col] layout.
__global__ __launch_bounds__(256, 2)
void k_chunk1(const unsigned short* __restrict__ xsc, const unsigned short* __restrict__ bcc,
              const float* __restrict__ dtb, const float* __restrict__ cumb,
              const float* __restrict__ Dp, const unsigned short* __restrict__ st,
              unsigned short* __restrict__ ybuf){
  __shared__ __align__(16) unsigned short Ml[128*CST];
  __shared__ __align__(16) unsigned short xsT[64*CST];
  __shared__ float cum_s[128], dt_s[128];
  const int blk = blockIdx.x, h = blk & 63, bc = blk >> 6;
  const size_t rowb = (size_t)bc * QCH;
  const int t = threadIdx.x, w = t >> 6, lane = t & 63, quad = lane >> 4, l16 = lane & 15;
  const int wrow = w * 32;
  if (t < 128){ cum_s[t] = cumb[(rowb + t)*64 + h]; dt_s[t] = dtb[(rowb + t)*64 + h]; }
  __syncthreads();
  // copy-transpose post-conv xs tile into xsT (no conv recompute)
#pragma unroll
  for (int it = 0; it < 2; it++){
    int idx = it * 256 + t;
    int q = idx & 127, p0 = (idx >> 7) * 16;
    const unsigned short* cur = xsc + (rowb + q) * 4096 + h * 64 + p0;
    short8 c0 = *(const short8*)cur, c1 = *(const short8*)(cur + 8);
#pragma unroll
    for (int j = 0; j < 16; j++)
      xsT[(p0 + j) * CST + q] = (unsigned short)(j < 8 ? c0[j] : c1[j-8]);
  }
  // CB = C @ B^T from post-conv bcc
  floatx4 acc[2][8] = {};
  const unsigned short* Cb = bcc + rowb * 256 + 128;
  const unsigned short* Bb = bcc + rowb * 256;
#pragma unroll
  for (int ks = 0; ks < 4; ks++){
    half8 af[2];
#pragma unroll
    for (int i = 0; i < 2; i++)
      af[i] = *(const half8*)(Cb + (size_t)(wrow + i*16 + l16) * 256 + ks*32 + quad*8);
#pragma unroll
    for (int j = 0; j < 8; j++){
      half8 bfr = *(const half8*)(Bb + (size_t)(j*16 + l16) * 256 + ks*32 + quad*8);
#pragma unroll
      for (int i = 0; i < 2; i++)
        acc[i][j] = __builtin_amdgcn_mfma_f32_16x16x32_f16(af[i], bfr, acc[i][j], 0, 0, 0);
    }
  }
  // M = CB * exp(cum_i - cum_j) * dt_j, causal, -> LDS fp16
#pragma unroll
  for (int i = 0; i < 2; i++)
#pragma unroll
    for (int j = 0; j < 8; j++){
      int jc = j*16 + l16;
      float dtj = dt_s[jc], cj = cum_s[jc];
#pragma unroll
      for (int r = 0; r < 4; r++){
        int ir = wrow + i*16 + quad*4 + r;
        float m = (ir >= jc) ? acc[i][j][r] * __expf(cum_s[ir] - cj) * dtj : 0.f;
        Ml[ir * CST + jc] = f2h(m);
      }
    }
  __syncthreads();
  // Yd = M @ xs
  floatx4 accY[2][4] = {};
#pragma unroll
  for (int ks = 0; ks < 4; ks++){
    half8 af[2], bfr[4];
#pragma unroll
    for (int i = 0; i < 2; i++)
      af[i] = *(const half8*)&Ml[(wrow + i*16 + l16)*CST + ks*32 + quad*8];
#pragma unroll
    for (int p = 0; p < 4; p++)
      bfr[p] = *(const half8*)&xsT[(p*16 + l16)*CST + ks*32 + quad*8];
#pragma unroll
    for (int i = 0; i < 2; i++)
#pragma unroll
      for (int p = 0; p < 4; p++)
        accY[i][p] = __builtin_amdgcn_mfma_f32_16x16x32_f16(af[i], bfr[p], accY[i][p], 0, 0, 0);
  }
  // ---- Yoff: stage Sprev (fp16) into Ml's LDS (stride CST), then C @ Sprev^T ----
  __syncthreads();                       // all Yd reads of Ml done
  unsigned short* Sp = Ml;               // reuse (64*CST <= 128*CST)
  {
    size_t base = ((size_t)bc * 64 + h) * 8192;
#pragma unroll
    for (int it = 0; it < 4; it++){
      int flat = it * 256 + t;           // [0,1024): 64 rows x 16 copies of 8
      int row = flat >> 4, col = (flat & 15) * 8;
      *(short8*)&Sp[row * CST + col] = *(const short8*)&st[base + (size_t)row * 128 + col];
    }
  }
  __syncthreads();
  floatx4 accO[2][4] = {};
#pragma unroll
  for (int ks = 0; ks < 4; ks++){
    half8 af[2], bfr[4];
#pragma unroll
    for (int i = 0; i < 2; i++)
      af[i] = *(const half8*)(Cb + (size_t)(wrow + i*16 + l16) * 256 + ks*32 + quad*8);
#pragma unroll
    for (int p = 0; p < 4; p++)
      bfr[p] = *(const half8*)&Sp[(p*16 + l16)*CST + ks*32 + quad*8];
#pragma unroll
    for (int i = 0; i < 2; i++)
#pragma unroll
      for (int p = 0; p < 4; p++)
        accO[i][p] = __builtin_amdgcn_mfma_f32_16x16x32_f16(af[i], bfr[p], accO[i][p], 0, 0, 0);
  }
  float Dh = Dp[h];
#pragma unroll
  for (int i = 0; i < 2; i++)
#pragma unroll
    for (int p = 0; p < 4; p++){
      int pc = p*16 + l16;
#pragma unroll
      for (int r = 0; r < 4; r++){
        int ir = wrow + i*16 + quad*4 + r;
        float y = accY[i][p][r] + __expf(cum_s[ir]) * accO[i][p][r] + Dh * h2f(xsT[pc*CST + ir]);
        ybuf[(rowb + ir) * (size_t)HIDN + h*64 + pc] = f2h(y);
      }
    }
}

// ---------------- per-(chunk,head): states[p][n] = sum_q xs[q][p]*wdec_q*B[q][n] ----------------
// Raw-tile staging; post-conv written back to global from registers.
__global__ __launch_bounds__(256, 2)
void k_chunk2(unsigned short* __restrict__ xsraw, const unsigned short* __restrict__ bcc,
              const unsigned short* __restrict__ halo, const float* __restrict__ cw,
              const float* __restrict__ dtb, const float* __restrict__ cumb,
              unsigned short* __restrict__ st){
  __shared__ __align__(16) unsigned short wBT[128*CST];
  __shared__ __align__(16) unsigned short xsT[64*CST];
  __shared__ __align__(16) unsigned short xsRaw[131*RST];
  __shared__ float cum_s[128], dt_s[128];
  __shared__ float cws[64*4];
  const int blk = blockIdx.x, h = blk & 63, bc = blk >> 6;
  const size_t rowb = (size_t)bc * QCH;
  const int t = threadIdx.x, w = t >> 6, lane = t & 63, quad = lane >> 4, l16 = lane & 15;
  if (t < 128){ cum_s[t] = cumb[(rowb + t)*64 + h]; dt_s[t] = dtb[(rowb + t)*64 + h]; }
  if (t < 64) *(float4*)&cws[t*4] = *(const float4*)&cw[((size_t)h*64 + t)*4];
  // stage raw slice: 131 rows x 8 chunks of 16B = 1048 chunks
#pragma unroll
  for (int it = 0; it < 5; it++){
    int flat = it * 256 + t;
    if (flat < 1048){
      int row = flat >> 3, c8 = (flat & 7) * 8;
      const unsigned short* src = (row < 3)
        ? halo + ((size_t)bc * 3 + row) * 4096 + h * 64 + c8
        : xsraw + (rowb + row - 3) * 4096 + h * 64 + c8;
      *(short8*)&xsRaw[row * RST + c8] = *(const short8*)src;
    }
  }
  __syncthreads();
  // conv + SiLU from LDS; write xsT (transposed) + post-conv back to global
  const int tl0 = (bc & 31) * QCH;
#pragma unroll
  for (int it = 0; it < 2; it++){
    int idx = it * 256 + t;
    int q = idx & 127, p0 = (idx >> 7) * 16;
    int tl = tl0 + q;
    int lr = q + 3;
    float f1 = (tl >= 1) ? 1.f : 0.f;
    float f2 = (tl >= 2) ? 1.f : 0.f;
    float f3 = (tl >= 3) ? 1.f : 0.f;
    short8 c0 = *(const short8*)&xsRaw[lr*RST + p0],     c1 = *(const short8*)&xsRaw[lr*RST + p0 + 8];
    short8 a0 = *(const short8*)&xsRaw[(lr-1)*RST + p0], a1 = *(const short8*)&xsRaw[(lr-1)*RST + p0 + 8];
    short8 b0 = *(const short8*)&xsRaw[(lr-2)*RST + p0], b1 = *(const short8*)&xsRaw[(lr-2)*RST + p0 + 8];
    short8 d0 = *(const short8*)&xsRaw[(lr-3)*RST + p0], d1 = *(const short8*)&xsRaw[(lr-3)*RST + p0 + 8];
    short8 w0, w1;
#pragma unroll
    for (int j = 0; j < 16; j++){
      int col = p0 + j;
      const float* wp = cws + col * 4;
      float vc = h2f((unsigned short)(j < 8 ? c0[j] : c1[j-8]));
      float v1 = h2f((unsigned short)(j < 8 ? a0[j] : a1[j-8]));
      float v2 = h2f((unsigned short)(j < 8 ? b0[j] : b1[j-8]));
      float v3 = h2f((unsigned short)(j < 8 ? d0[j] : d1[j-8]));
      float a = vc * wp[3] + f1 * v1 * wp[2] + f2 * v2 * wp[1] + f3 * v3 * wp[0];
      float s = a / (1.f + __expf(-a));
      unsigned short hv = f2h(s);
      xsT[col * CST + q] = hv;
      if (j < 8) w0[j] = (short)hv; else w1[j-8] = (short)hv;
    }
    unsigned short* g = xsraw + (rowb + q) * 4096 + h * 64 + p0;
    *(short8*)g = w0;
    *(short8*)(g + 8) = w1;
  }
  float clast = cum_s[127];
#pragma unroll
  for (int it = 0; it < 2; it++){                 // wBT[n][q] = B[q][n]*wdec_q
    int idx = it * 256 + t;
    int q = idx & 127, n0 = (idx >> 7) * 32;
    float wd = __expf(clast - cum_s[q]) * dt_s[q];
    const unsigned short* gp = bcc + (rowb + q) * 256 + n0;
#pragma unroll
    for (int c4 = 0; c4 < 4; c4++){
      short8 v = *(const short8*)(gp + c4*8);
#pragma unroll
      for (int jj = 0; jj < 8; jj++)
        wBT[(n0 + c4*8 + jj)*CST + q] = f2h(h2f((unsigned short)v[jj]) * wd);
    }
  }
  __syncthreads();
  floatx4 acc[8] = {};
#pragma unroll
  for (int ks = 0; ks < 4; ks++){
    half8 af = *(const half8*)&xsT[(w*16 + l16)*CST + ks*32 + quad*8];
#pragma unroll
    for (int j = 0; j < 8; j++){
      half8 bfr = *(const half8*)&wBT[(j*16 + l16)*CST + ks*32 + quad*8];
      acc[j] = __builtin_amdgcn_mfma_f32_16x16x32_f16(af, bfr, acc[j], 0, 0, 0);
    }
  }
  size_t base = ((size_t)bc * 64 + h) * 8192;
#pragma unroll
  for (int j = 0; j < 8; j++){
    int n = j*16 + l16;
#pragma unroll
    for (int r = 0; r < 4; r++){
      int p = w*16 + quad*4 + r;
      st[base + p*128 + n] = f2h(acc[j][r]);
    }
  }
}

// ---------------- sequential inter-chunk scan (fp16 states -> Sprev, in place) ----------------
__global__ void k_scan(unsigned short* __restrict__ st, const float* __restrict__ cumb){
  int id = blockIdx.x * 256 + threadIdx.x;  // [0, 2*64*64*64)
  int n2 = id & 63, p = (id >> 6) & 63, h = (id >> 12) & 63, b = id >> 18;
  float S0 = 0.f, S1 = 0.f;
  for (int c = 0; c < NCHUNK; c++){
    int bc = b * NCHUNK + c;
    size_t idx = ((size_t)bc * 64 + h) * 8192 + (size_t)p * 128 + n2 * 2;
    float dec = __expf(cumb[((size_t)bc * QCH + 127) * 64 + h]);
    unsigned v = *(const unsigned*)&st[idx];
    float v0 = h2f((unsigned short)(v & 0xffff));
    float v1 = h2f((unsigned short)(v >> 16));
    unsigned o = (unsigned)f2h(S0) | ((unsigned)f2h(S1) << 16);
    *(unsigned*)&st[idx] = o;
    S0 = S0 * dec + v0;
    S1 = S1 * dec + v1;
  }
}

// ---------------- gate y*silu(z) + RMSNorm, in-place fp16 (vectorized) ----------
__global__ __launch_bounds__(256)
void k_gate(unsigned short* __restrict__ yb, const unsigned short* __restrict__ zb,
            const float* __restrict__ nw){
  __shared__ float red[4];
  int row = blockIdx.x, t = threadIdx.x;
  size_t base = (size_t)row * HIDN + t * 16;
  short8 y0 = *(const short8*)&yb[base], y1 = *(const short8*)&yb[base + 8];
  short8 z0 = *(const short8*)&zb[base], z1 = *(const short8*)&zb[base + 8];
  float vals[16], ss = 0.f;
#pragma unroll
  for (int j = 0; j < 8; j++){
    float y = h2f((unsigned short)y0[j]);
    float z = h2f((unsigned short)z0[j]);
    float v = y * (z / (1.f + __expf(-z)));
    vals[j] = v; ss += v * v;
  }
#pragma unroll
  for (int j = 0; j < 8; j++){
    float y = h2f((unsigned short)y1[j]);
    float z = h2f((unsigned short)z1[j]);
    float v = y * (z / (1.f + __expf(-z)));
    vals[8 + j] = v; ss += v * v;
  }
  for (int o = 32; o > 0; o >>= 1) ss += __shfl_down(ss, o, 64);
  int w = t >> 6, lane = t & 63;
  if (lane == 0) red[w] = ss;
  __syncthreads();
  float scale = rsqrtf((red[0] + red[1] + red[2] + red[3]) / (float)HIDN + 1e-5f);
  const float4 nw0 = *(const float4*)&nw[t*16];
  const float4 nw1 = *(const float4*)&nw[t*16 + 4];
  const float4 nw2 = *(const float4*)&nw[t*16 + 8];
  const float4 nw3 = *(const float4*)&nw[t*16 + 12];
  float nwv[16] = { nw0.x, nw0.y, nw0.z, nw0.w, nw1.x, nw1.y, nw1.z, nw1.w,
                    nw2.x, nw2.y, nw2.z, nw2.w, nw3.x, nw3.y, nw3.z, nw3.w };
  short8 o0, o1;
#pragma unroll
  for (int j = 0; j < 8; j++){
    o0[j] = (short)f2h(vals[j] * scale * nwv[j]);
    o1[j] = (short)f2h(vals[8 + j] * scale * nwv[8 + j]);
  }
  *(short8*)&yb[base]     = o0;
  *(short8*)&yb[base + 8] = o1;
}

extern "C" void kernel_launch(void* const* d_in, const int* in_sizes, int n_in,
                              void* d_out, int out_size, void* d_ws, size_t ws_size,
                              hipStream_t stream){
  const float* x      = (const float*)d_in[0];
  const float* Win    = (const float*)d_in[1];
  const float* convw  = (const float*)d_in[2];
  const float* dtbias = (const float*)d_in[3];
  const float* Alog   = (const float*)d_in[4];
  const float* Dp     = (const float*)d_in[5];
  const float* nw     = (const float*)d_in[6];
  const float* Wout   = (const float*)d_in[7];
  float* out = (float*)d_out;

  char* ws = (char*)d_ws;
  size_t off = 0;
  auto alloc = [&](size_t bytes)->void*{ void* p = ws + off; off += (bytes + 255) & ~(size_t)255; return p; };
  unsigned short* xw    = (unsigned short*)alloc((size_t)ROWS * DIMK * 2);   // 33.5 MB (dead after gemm1)
  unsigned short* winb  = (unsigned short*)alloc((size_t)8448 * DIMK * 2);   // 34.6 MB (dead after gemm1)
  float*          dtraw = (float*)alloc((size_t)ROWS * 64 * 4);              // 2.1 MB
  unsigned short* woutb = (unsigned short*)alloc((size_t)DIMK * HIDN * 2);   // 16.8 MB
  unsigned short* zbuf  = (unsigned short*)alloc((size_t)ROWS * HIDN * 2);   // 67.1 MB
  unsigned short* xsraw = (unsigned short*)alloc((size_t)ROWS * HIDN * 2);   // 67.1 MB (pre-conv xs -> post-conv xs -> y)
  unsigned short* bcraw = (unsigned short*)alloc((size_t)ROWS * 256 * 2);    // 4.2 MB
  unsigned short* bcc   = (unsigned short*)alloc((size_t)ROWS * 256 * 2);    // 4.2 MB
  unsigned short* halo  = (unsigned short*)alloc((size_t)64 * 3 * 4096 * 2); // 1.5 MB
  float*          dtb   = (float*)alloc((size_t)ROWS * 64 * 4);              // 2.1 MB
  float*          cumb  = (float*)alloc((size_t)ROWS * 64 * 4);              // 2.1 MB
  // total ~224.5 MiB; states (fp16, 67.1 MB) overlays dead xw+winb region
  unsigned short* st    = xw;
  unsigned short* ybuf  = xsraw;   // chunk1 writes y in-place over post-conv xs

  k_prep<<<41472, 256, 0, stream>>>(x, Win, Wout, xw, winb, woutb);
  k_dtraw<<<ROWS/8, 256, 0, stream>>>(x, Win, dtraw);
  k_gemm1<<<dim3(1024), 512, 0, stream>>>(xw, winb, zbuf, xsraw);
  k_gemm1bc<<<dim3(4, 128), 256, 0, stream>>>(xw, winb, bcraw);
  k_mid<<<11280, 256, 0, stream>>>(bcraw, convw, bcc, xsraw, halo,
                                   dtraw, dtbias, Alog, dtb, cumb);
  k_chunk2<<<4096, 256, 0, stream>>>(xsraw, bcc, halo, convw, dtb, cumb, st);
  k_scan<<<2048, 256, 0, stream>>>(st, cumb);
  k_chunk1<<<4096, 256, 0, stream>>>(xsraw, bcc, dtb, cumb, Dp, st, ybuf);
  k_gate<<<ROWS, 256, 0, stream>>>(ybuf, zbuf, nw);
  k_gemm2<<<dim3(8*32), 512, 0, stream>>>(ybuf, woutb, out);
}